// Round 4
// baseline (199.469 us; speedup 1.0000x reference)
//
#include <hip/hip_runtime.h>

#define MU_F    136.72353790613718f
#define SIGMA_F 62.34640414043511f

// One WAVE per sample j; 4 waves (rows) per 256-thread block.
// Fused: last block to finish performs the deterministic final reduction.
// ws layout: [0, B) float losses; at byte offset B*4: one int ticket counter.
__global__ __launch_bounds__(256) void triplet_fused(
    const float* __restrict__ feats,
    const float* __restrict__ label,
    const int*   __restrict__ idx1,
    const int*   __restrict__ idx2,
    float* __restrict__ ws,
    int*   __restrict__ ticket,
    float* __restrict__ out,
    int B, int D)
{
    const int wid  = threadIdx.x >> 6;
    const int lane = threadIdx.x & 63;
    const int j    = blockIdx.x * 4 + wid;   // B % 4 == 0 -> always valid

    // --- replicate _fix_indices exactly ---
    const int r1 = idx1[j] % (B - 1);
    int aIdx = j + 1 + r1; if (aIdx >= B) aIdx -= B;          // a != j
    const int r2 = idx2[j] % (B - 1);
    int bIdx = j + 1 + r2; if (bIdx >= B) bIdx -= B;          // b != j
    if (bIdx == aIdx) {
        const int r2b = (idx2[j] + 1) % (B - 1);
        bIdx = j + 1 + r2b; if (bIdx >= B) bIdx -= B;         // b != a
    }

    // --- label values as the sequential scan would see them ---
    const float lj = label[j];
    float la = label[aIdx]; if (aIdx < j) la = (la - MU_F) / SIGMA_F;
    float lb = label[bIdx]; if (bIdx < j) lb = (lb - MU_F) / SIGMA_F;

    const float* __restrict__ fj = feats + (size_t)j    * (size_t)D;
    const float* __restrict__ fa = feats + (size_t)aIdx * (size_t)D;
    const float* __restrict__ fb = feats + (size_t)bIdx * (size_t)D;

    // --- full unroll: 8 iters x 3 float4 loads all in flight ---
    float pa = 0.f, pb = 0.f;
    #pragma unroll
    for (int it = 0; it < 8; ++it) {
        const int k = lane * 4 + it * 256;
        const float4 x = *(const float4*)(fj + k);
        const float4 a = *(const float4*)(fa + k);
        const float4 b = *(const float4*)(fb + k);
        float d;
        d = x.x - a.x; pa += d * d;   d = x.y - a.y; pa += d * d;
        d = x.z - a.z; pa += d * d;   d = x.w - a.w; pa += d * d;
        d = x.x - b.x; pb += d * d;   d = x.y - b.y; pb += d * d;
        d = x.z - b.z; pb += d * d;   d = x.w - b.w; pb += d * d;
    }

    // wave-local reduce (64 lanes)
    #pragma unroll
    for (int off = 32; off > 0; off >>= 1) {
        pa += __shfl_down(pa, off);
        pb += __shfl_down(pb, off);
    }

    if (lane == 0) {
        const float da = pa, db = pb;
        const float ld1 = fabsf(lj - la);
        const float ld2 = fabsf(lj - lb);
        const bool cond = (ld1 >= ld2);

        const float near_l = cond ? lb : la;
        const float far_l  = cond ? la : lb;
        const float dp     = cond ? db : da;
        const float dn     = cond ? da : db;

        const float li = (lj     - MU_F) / SIGMA_F;
        const float nl = (near_l - MU_F) / SIGMA_F;   // may double-normalize: matches reference
        const float fl = (far_l  - MU_F) / SIGMA_F;

        const float alpha = (li - fl) * (li - fl) - (li - nl) * (li - nl);
        const float loss  = dp - dn + 0.5f * alpha;
        ws[j] = loss > 0.f ? loss : 0.f;
    }

    // --- last-block-done final reduction (deterministic: one block, fixed order) ---
    __shared__ int sLast;
    __syncthreads();                      // all 4 ws[j] writes of this block issued
    if (threadIdx.x == 0) {
        __threadfence();                  // publish ws writes device-wide
        const int prev = atomicAdd(ticket, 1);
        sLast = (prev == gridDim.x - 1);
    }
    __syncthreads();
    if (sLast) {
        __threadfence();                  // acquire all other blocks' ws writes
        float s = 0.f;
        for (int k = threadIdx.x * 4; k < B; k += 256 * 4) {
            const float4 v = *(const float4*)(ws + k);
            s += (v.x + v.y) + (v.z + v.w);
        }
        #pragma unroll
        for (int off = 32; off > 0; off >>= 1) s += __shfl_down(s, off);
        __shared__ float sm[4];
        if (lane == 0) sm[wid] = s;
        __syncthreads();
        if (threadIdx.x == 0) out[0] = sm[0] + sm[1] + sm[2] + sm[3];
    }
}

extern "C" void kernel_launch(void* const* d_in, const int* in_sizes, int n_in,
                              void* d_out, int out_size, void* d_ws, size_t ws_size,
                              hipStream_t stream)
{
    const float* feats = (const float*)d_in[0];
    const float* label = (const float*)d_in[1];
    const int*   idx1  = (const int*)d_in[2];
    const int*   idx2  = (const int*)d_in[3];

    const int B = in_sizes[1];             // 16384
    const int D = in_sizes[0] / B;         // 2048

    float* ws     = (float*)d_ws;          // B floats of loss scratch
    int*   ticket = (int*)((char*)d_ws + (size_t)B * sizeof(float));

    // zero the ticket each call (graph-capture-safe async memset)
    hipMemsetAsync(ticket, 0, sizeof(int), stream);

    triplet_fused<<<B / 4, 256, 0, stream>>>(feats, label, idx1, idx2,
                                             ws, ticket, (float*)d_out, B, D);
}

// Round 5
// 85.415 us; speedup vs baseline: 2.3353x; 2.3353x over previous
//
#include <hip/hip_runtime.h>

#define MU_F    136.72353790613718f
#define SIGMA_F 62.34640414043511f

// One WAVE (64 lanes) per sample j; 4 rows per 256-thread block.
// Round-3 main loop (proven 6.7 TB/s effective). Reduction fused via ONE
// relaxed float atomicAdd per block (no threadfence -> no L2 wb/inv storms).
__global__ __launch_bounds__(256) void triplet_atomic(
    const float* __restrict__ feats,
    const float* __restrict__ label,
    const int*   __restrict__ idx1,
    const int*   __restrict__ idx2,
    float* __restrict__ out,
    int B, int D)
{
    const int wid  = threadIdx.x >> 6;
    const int lane = threadIdx.x & 63;
    const int j    = blockIdx.x * 4 + wid;   // grid = B/4 exactly (B % 4 == 0)

    // --- replicate _fix_indices exactly ---
    const int r1 = idx1[j] % (B - 1);
    int aIdx = j + 1 + r1; if (aIdx >= B) aIdx -= B;          // a != j
    const int r2 = idx2[j] % (B - 1);
    int bIdx = j + 1 + r2; if (bIdx >= B) bIdx -= B;          // b != j
    if (bIdx == aIdx) {
        const int r2b = (idx2[j] + 1) % (B - 1);
        bIdx = j + 1 + r2b; if (bIdx >= B) bIdx -= B;         // b != a
    }

    // --- label values as the sequential scan would see them ---
    const float lj = label[j];
    float la = label[aIdx]; if (aIdx < j) la = (la - MU_F) / SIGMA_F;
    float lb = label[bIdx]; if (bIdx < j) lb = (lb - MU_F) / SIGMA_F;

    const float* __restrict__ fj = feats + (size_t)j    * (size_t)D;
    const float* __restrict__ fa = feats + (size_t)aIdx * (size_t)D;
    const float* __restrict__ fb = feats + (size_t)bIdx * (size_t)D;

    // --- row distance partials (round-3 schedule: unroll 4, ~12 loads in flight) ---
    float pa = 0.f, pb = 0.f;
    #pragma unroll 4
    for (int k = lane * 4; k < D; k += 64 * 4) {
        const float4 x = *(const float4*)(fj + k);
        const float4 a = *(const float4*)(fa + k);
        const float4 b = *(const float4*)(fb + k);
        float d;
        d = x.x - a.x; pa += d * d;   d = x.y - a.y; pa += d * d;
        d = x.z - a.z; pa += d * d;   d = x.w - a.w; pa += d * d;
        d = x.x - b.x; pb += d * d;   d = x.y - b.y; pb += d * d;
        d = x.z - b.z; pb += d * d;   d = x.w - b.w; pb += d * d;
    }

    // wave-local butterfly reduce (64 lanes)
    #pragma unroll
    for (int off = 32; off > 0; off >>= 1) {
        pa += __shfl_down(pa, off);
        pb += __shfl_down(pb, off);
    }

    __shared__ float sLoss[4];
    if (lane == 0) {
        const float da = pa, db = pb;
        const float ld1 = fabsf(lj - la);
        const float ld2 = fabsf(lj - lb);
        const bool cond = (ld1 >= ld2);

        const float near_l = cond ? lb : la;
        const float far_l  = cond ? la : lb;
        const float dp     = cond ? db : da;
        const float dn     = cond ? da : db;

        const float li = (lj     - MU_F) / SIGMA_F;
        const float nl = (near_l - MU_F) / SIGMA_F;   // may double-normalize: matches reference
        const float fl = (far_l  - MU_F) / SIGMA_F;

        const float alpha = (li - fl) * (li - fl) - (li - nl) * (li - nl);
        const float loss  = dp - dn + 0.5f * alpha;
        sLoss[wid] = loss > 0.f ? loss : 0.f;
    }
    __syncthreads();

    // one relaxed device-scope atomic per block -- no fences
    if (threadIdx.x == 0) {
        atomicAdd(out, (sLoss[0] + sLoss[1]) + (sLoss[2] + sLoss[3]));
    }
}

extern "C" void kernel_launch(void* const* d_in, const int* in_sizes, int n_in,
                              void* d_out, int out_size, void* d_ws, size_t ws_size,
                              hipStream_t stream)
{
    const float* feats = (const float*)d_in[0];
    const float* label = (const float*)d_in[1];
    const int*   idx1  = (const int*)d_in[2];
    const int*   idx2  = (const int*)d_in[3];

    const int B = in_sizes[1];             // 16384
    const int D = in_sizes[0] / B;         // 2048

    // zero the accumulator each call (graph-capture-safe; keeps replays correct)
    hipMemsetAsync(d_out, 0, sizeof(float), stream);

    triplet_atomic<<<B / 4, 256, 0, stream>>>(feats, label, idx1, idx2,
                                              (float*)d_out, B, D);
}

// Round 6
// 63.237 us; speedup vs baseline: 3.1543x; 1.3507x over previous
//
#include <hip/hip_runtime.h>

#define MU_F    136.72353790613718f
#define SIGMA_F 62.34640414043511f

// One WAVE (64 lanes) per sample j; 4 rows per 256-thread block.
// Wave-local reduce only: no LDS, no __syncthreads, no atomics.
// (Round-3 structure: proven 65.9 us total; fused-atomic variant regressed
//  to 85 us from 4096 same-address atomicAdd serialization.)
__global__ __launch_bounds__(256) void triplet_wave_per_row(
    const float* __restrict__ feats,
    const float* __restrict__ label,
    const int*   __restrict__ idx1,
    const int*   __restrict__ idx2,
    float* __restrict__ ws,
    int B, int D)
{
    const int wid  = threadIdx.x >> 6;
    const int lane = threadIdx.x & 63;
    const int j    = blockIdx.x * 4 + wid;   // grid = B/4 exactly (B % 4 == 0)

    // --- replicate _fix_indices exactly ---
    const int r1 = idx1[j] % (B - 1);
    int aIdx = j + 1 + r1; if (aIdx >= B) aIdx -= B;          // a != j
    const int r2 = idx2[j] % (B - 1);
    int bIdx = j + 1 + r2; if (bIdx >= B) bIdx -= B;          // b != j
    if (bIdx == aIdx) {
        const int r2b = (idx2[j] + 1) % (B - 1);
        bIdx = j + 1 + r2b; if (bIdx >= B) bIdx -= B;         // b != a
    }

    // --- label values as the sequential scan would see them ---
    const float lj = label[j];
    float la = label[aIdx]; if (aIdx < j) la = (la - MU_F) / SIGMA_F;
    float lb = label[bIdx]; if (bIdx < j) lb = (lb - MU_F) / SIGMA_F;

    const float* __restrict__ fj = feats + (size_t)j    * (size_t)D;
    const float* __restrict__ fa = feats + (size_t)aIdx * (size_t)D;
    const float* __restrict__ fb = feats + (size_t)bIdx * (size_t)D;

    // --- row distance partials: 8 float4 per row per lane at D=2048 ---
    float pa = 0.f, pb = 0.f;
    #pragma unroll 4
    for (int k = lane * 4; k < D; k += 64 * 4) {
        const float4 x = *(const float4*)(fj + k);
        const float4 a = *(const float4*)(fa + k);
        const float4 b = *(const float4*)(fb + k);
        float d;
        d = x.x - a.x; pa += d * d;   d = x.y - a.y; pa += d * d;
        d = x.z - a.z; pa += d * d;   d = x.w - a.w; pa += d * d;
        d = x.x - b.x; pb += d * d;   d = x.y - b.y; pb += d * d;
        d = x.z - b.z; pb += d * d;   d = x.w - b.w; pb += d * d;
    }

    // wave-local butterfly reduce (64 lanes)
    #pragma unroll
    for (int off = 32; off > 0; off >>= 1) {
        pa += __shfl_down(pa, off);
        pb += __shfl_down(pb, off);
    }

    if (lane == 0) {
        const float da = pa, db = pb;

        const float ld1 = fabsf(lj - la);
        const float ld2 = fabsf(lj - lb);
        const bool cond = (ld1 >= ld2);

        const float near_l = cond ? lb : la;
        const float far_l  = cond ? la : lb;
        const float dp     = cond ? db : da;
        const float dn     = cond ? da : db;

        const float li = (lj     - MU_F) / SIGMA_F;
        const float nl = (near_l - MU_F) / SIGMA_F;   // may double-normalize: matches reference
        const float fl = (far_l  - MU_F) / SIGMA_F;

        const float alpha = (li - fl) * (li - fl) - (li - nl) * (li - nl);
        const float loss  = dp - dn + 0.5f * alpha;
        ws[j] = loss > 0.f ? loss : 0.f;
    }
}

// Deterministic single-block reduction of B partials into out[0].
// 1024 threads, float4 loads, fixed summation order -> bitwise stable.
__global__ __launch_bounds__(1024) void reduce_losses(
    const float* __restrict__ ws, float* __restrict__ out, int n)
{
    float s = 0.f;
    for (int k = threadIdx.x * 4; k < n; k += 1024 * 4) {
        const float4 v = *(const float4*)(ws + k);
        s += (v.x + v.y) + (v.z + v.w);
    }
    #pragma unroll
    for (int off = 32; off > 0; off >>= 1) s += __shfl_down(s, off);
    __shared__ float sm[16];
    const int wid = threadIdx.x >> 6, lane = threadIdx.x & 63;
    if (lane == 0) sm[wid] = s;
    __syncthreads();
    if (threadIdx.x == 0) {
        float t = 0.f;
        #pragma unroll
        for (int w = 0; w < 16; ++w) t += sm[w];
        out[0] = t;
    }
}

extern "C" void kernel_launch(void* const* d_in, const int* in_sizes, int n_in,
                              void* d_out, int out_size, void* d_ws, size_t ws_size,
                              hipStream_t stream)
{
    const float* feats = (const float*)d_in[0];
    const float* label = (const float*)d_in[1];
    const int*   idx1  = (const int*)d_in[2];
    const int*   idx2  = (const int*)d_in[3];

    const int B = in_sizes[1];             // 16384
    const int D = in_sizes[0] / B;         // 2048

    float* ws = (float*)d_ws;              // B floats of scratch

    triplet_wave_per_row<<<B / 4, 256, 0, stream>>>(feats, label, idx1, idx2, ws, B, D);
    reduce_losses<<<1, 1024, 0, stream>>>(ws, (float*)d_out, B);
}